// Round 11
// baseline (310.092 us; speedup 1.0000x reference)
//
#include <hip/hip_runtime.h>

// Trilinear 3D-LUT apply: lut [1,3,33,33,33] f32, x [8,3,1024,1024] f32 in [0,1)
// out [8,3,1024,1024] f32.
//
// V10 = OCCUPANCY DOUBLING, de-confounded. V5 failed because (1024,8) +
//   non-pipelined structure let the RA collapse to 32 VGPR and scalarize the
//   x loads. This version keeps V6's exact pipeline structure -- which
//   compiled to 52 VGPR three times (V6/V9), inside the 64-VGPR cap that
//   8 waves/EU requires -- and only changes the LDS cube to fp16 singles:
//   35937 * 2 = 71,874 B -> 2 blocks/CU -> 32 waves/CU (2x latency cover).
// Math: 8x ds_read_u16 + v_cvt_f32_f16, then V6's f32 lerp chain (avoid V7's
//   thin dot2 body). Co-resident blocks are (c,chunk),(c+1,chunk) -> shared x.
// Resource model at 79.5us (V6): HBM 40%, LDS ~45%, VALU 34%, all idle-heavy;
//   2x waves compresses idle toward the LDS-busy floor (~46us).
//
// Success criteria: VGPR 52-64 (NOT ~32), Occupancy ~60-70%, HBM 4.2-5 TB/s,
//   dispatch 55-65us. If VGPR <= 40: RA collapse again -> revert to V6.

#define D   33
#define D2  (33 * 33)
#define D3  (33 * 33 * 33)       // 35937 fp16 = 71,874 B LDS -> 2 blocks/CU
#define HW  (1024 * 1024)
#define QHW (HW / 4)             // float4 groups per plane = 2^18
#define CHUNKS 256
#define GPC ((8 * QHW) / CHUNKS) // groups per chunk = 8192
#define THREADS 1024
#define ITERS (GPC / THREADS)    // 8 float4-groups per thread

typedef __fp16 h16;

// min 8 waves/EU (= 2 blocks/CU at 1024 threads): caps VGPR at 64.
__global__ __launch_bounds__(THREADS, 8) void lut3d_kernel(
    const float* __restrict__ lut, const float* __restrict__ x,
    float* __restrict__ out)
{
    const int c     = blockIdx.x;   // channel fastest: co-resident blocks share x
    const int chunk = blockIdx.y;

    // --- stage one channel cube as fp16 singles -----------------------------
    __shared__ h16 ls[D3];
    {
        const float* lc = lut + c * D3;
        for (int i = threadIdx.x; i < D3; i += THREADS) ls[i] = (h16)lc[i];
    }
    __syncthreads();

    const int tid  = threadIdx.x;
    const int base = chunk * GPC;            // chunk never straddles a batch plane
    const int bidx = base >> 18;             // batch index, block-constant
    const int pb   = (base & (QHW - 1)) * 4; // float offset of chunk in plane

    const float* xp = x   + (size_t)bidx * 3 * HW + pb;
    float*       op = out + (size_t)bidx * 3 * HW + (size_t)c * HW + pb;

    // load the 3 channel float4s of group `it`
    auto LD = [&](int it, float4& r, float4& g, float4& b) {
        const int fo = it * (THREADS * 4) + tid * 4;
        r = *(const float4*)(xp + fo);
        g = *(const float4*)(xp + fo + HW);
        b = *(const float4*)(xp + fo + 2 * HW);
    };

    // compute + store one float4-group (4 pixels)
    auto DO = [&](int it, const float4& xr, const float4& xg, const float4& xB) {
        const float rr[4] = {xr.x, xr.y, xr.z, xr.w};
        const float gg[4] = {xg.x, xg.y, xg.z, xg.w};
        const float bb[4] = {xB.x, xB.y, xB.z, xB.w};
        float oo[4];
        #pragma unroll
        for (int j = 0; j < 4; ++j) {
            // clamp(x,0,1)*32 capped below 32: i0<=31 always -> +1/+33/+1089
            // neighbor offsets are compile-time constants (const ds offsets).
            const float vr = fminf(fmaxf(rr[j], 0.f) * 32.f, 31.999998f);
            const float vg = fminf(fmaxf(gg[j], 0.f) * 32.f, 31.999998f);
            const float vb = fminf(fmaxf(bb[j], 0.f) * 32.f, 31.999998f);

            const int r0 = (int)vr, g0 = (int)vg, b0 = (int)vb;  // trunc==floor
            const float fr = vr - (float)r0;
            const float fg = vg - (float)g0;
            const float fb = vb - (float)b0;

            const int idx = __mul24(r0, D2) + __mul24(g0, D) + b0;

            const float c000 = (float)ls[idx];
            const float c001 = (float)ls[idx + 1];
            const float c010 = (float)ls[idx + D];
            const float c011 = (float)ls[idx + D + 1];
            const float c100 = (float)ls[idx + D2];
            const float c101 = (float)ls[idx + D2 + 1];
            const float c110 = (float)ls[idx + D2 + D];
            const float c111 = (float)ls[idx + D2 + D + 1];

            const float c00 = c000 + fb * (c001 - c000);
            const float c01 = c010 + fb * (c011 - c010);
            const float c10 = c100 + fb * (c101 - c100);
            const float c11 = c110 + fb * (c111 - c110);
            const float c0  = c00 + fg * (c01 - c00);
            const float c1  = c10 + fg * (c11 - c10);
            oo[j] = c0 + fr * (c1 - c0);
        }
        const int fo = it * (THREADS * 4) + tid * 4;
        *(float4*)(op + fo) = make_float4(oo[0], oo[1], oo[2], oo[3]);
    };

    // --- enforced 2-deep software pipeline (V6-proven, 52 VGPR) -------------
    float4 ar, ag, ab_, br, bg, bb_;
    LD(0, ar, ag, ab_);
    LD(1, br, bg, bb_);

    #pragma unroll 1
    for (int it = 0; it < ITERS - 2; it += 2) {
        float4 nr, ng, nb_, mr, mg, mb_;
        LD(it + 2, nr, ng, nb_);             // issue next pair's 6 loads FIRST
        LD(it + 3, mr, mg, mb_);
        __builtin_amdgcn_sched_barrier(0);   // loads may not sink below
        DO(it,     ar, ag, ab_);
        DO(it + 1, br, bg, bb_);
        ar = nr; ag = ng; ab_ = nb_;
        br = mr; bg = mg; bb_ = mb_;
    }
    DO(ITERS - 2, ar, ag, ab_);              // drain
    DO(ITERS - 1, br, bg, bb_);
}

extern "C" void kernel_launch(void* const* d_in, const int* in_sizes, int n_in,
                              void* d_out, int out_size, void* d_ws, size_t ws_size,
                              hipStream_t stream) {
    const float* lut = (const float*)d_in[0];   // [1,3,33,33,33]
    const float* x   = (const float*)d_in[1];   // [8,3,1024,1024]
    float* out = (float*)d_out;                 // [8,3,1024,1024]

    dim3 grid(3, CHUNKS);
    lut3d_kernel<<<grid, THREADS, 0, stream>>>(lut, x, out);
}